// Round 4
// baseline (314.002 us; speedup 1.0000x reference)
//
#include <hip/hip_runtime.h>
#include <hip/hip_bf16.h>

// ConvCls partial-FC 1x1-conv classifier, fp32 via bf16 hi/lo 3-pass MFMA.
// out[b,u,hw] = sum_c x[b,c,hw] * W[sorted[u], c] + bias[sorted[u]]
// Flattened GEMM: C[m, u], m = b*49+hw, M = 25088 = 128*196 (exact, no padding).
#define CIN    512
#define BATCH  512
#define HW     49
#define UDIM   512
#define MTOT   (BATCH * HW)     // 25088
#define MT     128              // m-tile per block
#define NMB    (MTOT / MT)      // 196
#define UHALF  256              // u per block
#define KT     16               // K per pipeline step
#define NSTEP  (CIN / KT)       // 32
#define NBLK   (NMB * 2)        // 392 = 8 * 49 (bijective XCD swizzle)

typedef short  bf16x8 __attribute__((ext_vector_type(8)));
typedef short  s16x4  __attribute__((ext_vector_type(4)));
typedef float  f32x16 __attribute__((ext_vector_type(16)));

#define MFMA32(A, B, C) __builtin_amdgcn_mfma_f32_32x32x16_bf16((A), (B), (C), 0, 0, 0)

__device__ __forceinline__ void gload_lds16(const void* g, void* l) {
  __builtin_amdgcn_global_load_lds(
      (const __attribute__((address_space(1))) void*)g,
      (__attribute__((address_space(3))) void*)l, 16, 0, 0);
}

// fp32 -> bf16 hi/lo split (RNE via bit trick; inputs are finite randoms)
__device__ __forceinline__ void split2(float v, unsigned short& h, unsigned short& l) {
  unsigned int b  = __float_as_uint(v);
  unsigned int hb = (b + 0x7FFFu + ((b >> 16) & 1u)) >> 16;
  float hf        = __uint_as_float(hb << 16);
  unsigned int lb = __float_as_uint(v - hf);
  h = (unsigned short)hb;
  l = (unsigned short)((lb + 0x7FFFu + ((lb >> 16) & 1u)) >> 16);
}

__device__ __forceinline__ f32x16 zero16() {
  f32x16 r;
#pragma unroll
  for (int i = 0; i < 16; ++i) r[i] = 0.f;
  return r;
}

// ---- Kernel 1: rank-sort distinct labels, gather bias subset ----------------
__global__ void sort_gather(const int* __restrict__ labels,
                            const float* __restrict__ bias,
                            int* __restrict__ sorted,
                            float* __restrict__ bsub)
{
  __shared__ int sl[BATCH];
  const int i = threadIdx.x;
  const int stride = (labels[1] == 0) ? 2 : 1;  // int64-layout hedge
  const int li = labels[i * stride];
  sl[i] = li;
  __syncthreads();
  int rank = 0;
#pragma unroll 8
  for (int j = 0; j < BATCH; ++j) rank += (sl[j] < li) ? 1 : 0;
  sorted[rank] = li;
  bsub[rank]   = bias[li];
}

// ---- Kernel 2: gather W rows, split, MFMA-fragment order --------------------
// layout: W?[ s(32) ][ kq(2) ][ u(512) ][ j(8) ],  k = s*16 + kq*8 + j
__global__ void wprep(const float* __restrict__ weight,
                      const int* __restrict__ sorted,
                      unsigned short* __restrict__ whi,
                      unsigned short* __restrict__ wlo)
{
  const int u   = blockIdx.x;
  const int lbl = sorted[u];
  const float* wrow = weight + (size_t)lbl * CIN;
  for (int k = threadIdx.x; k < CIN; k += 256) {
    unsigned short h, l;
    split2(wrow[k], h, l);
    const int s = k >> 4, kq = (k >> 3) & 1, j = k & 7;
    const size_t idx = (((size_t)(s * 2 + kq)) * UDIM + u) * 8 + j;
    whi[idx] = h;
    wlo[idx] = l;
  }
}

// ---- Kernel 3: main GEMM, m-tiled, u-halved, 2-phase pipeline ---------------
__global__ __launch_bounds__(512, 4) void convcls_main(
    const float* __restrict__ x,
    const unsigned short* __restrict__ whi,
    const unsigned short* __restrict__ wlo,
    const float* __restrict__ bsub,
    float* __restrict__ out)
{
  __shared__ __attribute__((aligned(16))) unsigned short WhB[2][2][UHALF][8]; // 16 KB
  __shared__ __attribute__((aligned(16))) unsigned short WlB[2][2][UHALF][8]; // 16 KB
  __shared__ __attribute__((aligned(16))) unsigned short XhB[2][2][MT][8];    //  8 KB
  __shared__ __attribute__((aligned(16))) unsigned short XlB[2][2][MT][8];    //  8 KB

  const int bid = blockIdx.x;
  // XCD-chunked bijective swizzle: each XCD gets 49 consecutive work items;
  // work id = uh*196 + mb, so XCDs 0-3 own uh=0, XCDs 4-7 own uh=1 (196=4*49).
  const int swz = (bid & 7) * (NBLK / 8) + (bid >> 3);
  const int uh  = swz / NMB;
  const int mb  = swz - uh * NMB;

  const int tid  = threadIdx.x;
  const int wave = tid >> 6, lane = tid & 63;
  const int l31  = lane & 31, lq = lane >> 5;

  // X staging duty: thread -> (mloc, 4 consecutive k)
  const int mloc = tid & 127;
  const int ks   = tid >> 7;            // 0..3
  const int kqs  = ks >> 1;
  const int j0   = (ks & 1) * 4;
  const int mg   = mb * MT + mloc;
  const int bimg = mg / HW;
  const int hwp  = mg - bimg * HW;
  const float* xsrc = x + (size_t)bimg * (CIN * HW) + hwp;

  // W staging duty: chunk = wave (512 bf16 = 1 KB), kq = wave>>2, u-off (wave&3)*64
  const size_t wsrcbase =
      ((size_t)(wave >> 2) * UDIM + uh * UHALF + (wave & 3) * 64) * 8 + lane * 8;

  f32x16 a00 = zero16(), a01 = zero16(), a10 = zero16(), a11 = zero16();

  const int uoff = (wave & 3) * 64;  // wave's u sub-tile base within UHALF
  const int moff = (wave >> 2) * 64; // wave's m sub-tile base within MT

  // ---- prologue: stage step 0 into buffer 0 ----
  {
    float v[4];
#pragma unroll
    for (int i = 0; i < 4; ++i) v[i] = xsrc[(size_t)(ks * 4 + i) * HW];
    gload_lds16(whi + wsrcbase, (char*)&WhB[0][0][0][0] + wave * 1024);
    gload_lds16(wlo + wsrcbase, (char*)&WlB[0][0][0][0] + wave * 1024);
    s16x4 ph, pl;
#pragma unroll
    for (int i = 0; i < 4; ++i) {
      unsigned short h, l; split2(v[i], h, l);
      ph[i] = (short)h; pl[i] = (short)l;
    }
    *(s16x4*)&XhB[0][kqs][mloc][j0] = ph;
    *(s16x4*)&XlB[0][kqs][mloc][j0] = pl;
  }
  __syncthreads();

  // ---- main loop: one barrier per step; step s+1 loads overlap MFMA ----
  for (int s = 0; s < NSTEP; ++s) {
    const int cur = s & 1, nxt = cur ^ 1;
    const bool pf = (s + 1 < NSTEP);   // block-uniform
    float v[4];
    if (pf) {
      const size_t so = (size_t)(s + 1) * (2 * UDIM * 8);
      gload_lds16(whi + so + wsrcbase, (char*)&WhB[nxt][0][0][0] + wave * 1024);
      gload_lds16(wlo + so + wsrcbase, (char*)&WlB[nxt][0][0][0] + wave * 1024);
#pragma unroll
      for (int i = 0; i < 4; ++i)
        v[i] = xsrc[(size_t)((s + 1) * KT + ks * 4 + i) * HW];
    }

    bf16x8 ah0 = *(const bf16x8*)&WhB[cur][lq][uoff + l31][0];
    bf16x8 ah1 = *(const bf16x8*)&WhB[cur][lq][uoff + 32 + l31][0];
    bf16x8 al0 = *(const bf16x8*)&WlB[cur][lq][uoff + l31][0];
    bf16x8 al1 = *(const bf16x8*)&WlB[cur][lq][uoff + 32 + l31][0];
    bf16x8 bh0 = *(const bf16x8*)&XhB[cur][lq][moff + l31][0];
    bf16x8 bh1 = *(const bf16x8*)&XhB[cur][lq][moff + 32 + l31][0];
    bf16x8 bl0 = *(const bf16x8*)&XlB[cur][lq][moff + l31][0];
    bf16x8 bl1 = *(const bf16x8*)&XlB[cur][lq][moff + 32 + l31][0];

    // 12 MFMA: 2 u-tiles x 2 m-tiles x 3 split passes (A=W rows->u, B=X rows->m)
    a00 = MFMA32(ah0, bh0, a00);  a01 = MFMA32(ah0, bh1, a01);
    a10 = MFMA32(ah1, bh0, a10);  a11 = MFMA32(ah1, bh1, a11);
    a00 = MFMA32(ah0, bl0, a00);  a01 = MFMA32(ah0, bl1, a01);
    a10 = MFMA32(ah1, bl0, a10);  a11 = MFMA32(ah1, bl1, a11);
    a00 = MFMA32(al0, bh0, a00);  a01 = MFMA32(al0, bh1, a01);
    a10 = MFMA32(al1, bh0, a10);  a11 = MFMA32(al1, bh1, a11);

    if (pf) {  // stage next X (nxt buffer; race-free: its last readers were step s-1)
      s16x4 ph, pl;
#pragma unroll
      for (int i = 0; i < 4; ++i) {
        unsigned short h, l; split2(v[i], h, l);
        ph[i] = (short)h; pl[i] = (short)l;
      }
      *(s16x4*)&XhB[nxt][kqs][mloc][j0] = ph;
      *(s16x4*)&XlB[nxt][kqs][mloc][j0] = pl;
    }
    // barrier drains vmcnt (W[s+1] gloads) + lgkmcnt (X[s+1] writes) — exactly
    // the visibility needed, placed after the MFMA block.
    __syncthreads();
  }

  // ---- epilogue: bias + store (no masking needed: M is exact) ----
  // C/D 32x32 layout: col = lane&31 (m), row = (r&3) + 8*(r>>2) + 4*(lane>>5) (u)
  const int u0g = uh * UHALF + uoff;
  const int m0g = mb * MT + moff;
  const int mA  = m0g + l31,      mB = m0g + 32 + l31;
  const int bA  = mA / HW,        hA = mA - bA * HW;
  const int bB  = mB / HW,        hB = mB - bB * HW;
  float* oA = out + (size_t)bA * (UDIM * HW) + hA;
  float* oB = out + (size_t)bB * (UDIM * HW) + hB;
#pragma unroll
  for (int r = 0; r < 16; ++r) {
    const int urow = (r & 3) + 8 * (r >> 2) + 4 * lq;
    {
      const int u = u0g + urow;
      const float bs = bsub[u];
      oA[(size_t)u * HW] = a00[r] + bs;
      oB[(size_t)u * HW] = a01[r] + bs;
    }
    {
      const int u = u0g + 32 + urow;
      const float bs = bsub[u];
      oA[(size_t)u * HW] = a10[r] + bs;
      oB[(size_t)u * HW] = a11[r] + bs;
    }
  }
}

extern "C" void kernel_launch(void* const* d_in, const int* in_sizes, int n_in,
                              void* d_out, int out_size, void* d_ws, size_t ws_size,
                              hipStream_t stream)
{
  const float* x      = (const float*)d_in[0];
  const int*   labels = (const int*)d_in[1];
  const float* weight = (const float*)d_in[2];
  const float* bias   = (const float*)d_in[3];
  float*       out    = (float*)d_out;

  int*            sorted = (int*)d_ws;                                 // 2 KB
  float*          bsub   = (float*)((char*)d_ws + 2048);               // 2 KB
  unsigned short* whi    = (unsigned short*)((char*)d_ws + 4096);      // 512 KB
  unsigned short* wlo    = (unsigned short*)((char*)d_ws + 4096 + 512 * 1024);

  sort_gather<<<1, BATCH, 0, stream>>>(labels, bias, sorted, bsub);
  wprep<<<UDIM, 256, 0, stream>>>(weight, sorted, whi, wlo);
  convcls_main<<<NBLK, 512, 0, stream>>>(x, whi, wlo, bsub, out);
}